// Round 1
// baseline (447.289 us; speedup 1.0000x reference)
//
#include <hip/hip_runtime.h>

// IDWT (inverse Haar, single level).
// Inputs: LL, LH, HL, HH each [B=16, C=64, h=128, w=128] fp32.
// Haar matrices (d_in[4..7]) are fixed banded +-1/sqrt(2) -> the three
// matmuls reduce to a per-element butterfly writing a 2x2 output block:
//   out[2i,2j]     = 0.5*(LL - LH - HL + HH)
//   out[2i,2j+1]   = 0.5*(LL + LH - HL - HH)
//   out[2i+1,2j]   = 0.5*(LL - LH + HL - HH)
//   out[2i+1,2j+1] = 0.5*(LL + LH + HL + HH)
// Pure streaming op: 256 MiB in + 256 MiB out -> HBM-bound (~90us @ 6 TB/s).

__global__ __launch_bounds__(256) void idwt_haar_kernel(
    const float* __restrict__ LL,
    const float* __restrict__ LH,
    const float* __restrict__ HL,
    const float* __restrict__ HH,
    float* __restrict__ out,
    int n_quads)  // total float4 quads per input = B*C*h*w/4
{
    constexpr int OW = 256;  // output width (2*w)

    const int stride = gridDim.x * blockDim.x;
    for (int q = blockIdx.x * blockDim.x + threadIdx.x; q < n_quads;
         q += stride) {
        // q indexes a float4 (4 consecutive j's) within the flattened input.
        // Input row length = 128 floats = 32 quads.
        const int r  = q >> 5;        // flattened (b,c,i) row index
        const int tj = q & 31;       // quad index within the row
        const int j0 = tj << 2;      // starting j (0..124, step 4)

        const float4 ll = reinterpret_cast<const float4*>(LL)[q];
        const float4 lh = reinterpret_cast<const float4*>(LH)[q];
        const float4 hl = reinterpret_cast<const float4*>(HL)[q];
        const float4 hh = reinterpret_cast<const float4*>(HH)[q];

        const int p = r >> 7;        // image index b*C + c  (h = 128)
        const int i = r & 127;       // input row within image

        // Output base: image p, row 2i, col 2*j0. 2*j0 is a multiple of 8
        // -> 32B aligned, float4 stores are safe.
        const size_t obase =
            (size_t)p * (OW * OW) + (size_t)(2 * i) * OW + (size_t)(2 * j0);

        const float a[4] = {ll.x, ll.y, ll.z, ll.w};
        const float b[4] = {lh.x, lh.y, lh.z, lh.w};
        const float c[4] = {hl.x, hl.y, hl.z, hl.w};
        const float d[4] = {hh.x, hh.y, hh.z, hh.w};

        float row0[8], row1[8];
#pragma unroll
        for (int k = 0; k < 4; ++k) {
            const float A = a[k], B = b[k], C = c[k], D = d[k];
            row0[2 * k]     = 0.5f * (A - B - C + D);
            row0[2 * k + 1] = 0.5f * (A + B - C - D);
            row1[2 * k]     = 0.5f * (A - B + C - D);
            row1[2 * k + 1] = 0.5f * (A + B + C + D);
        }

        float4* o0 = reinterpret_cast<float4*>(out + obase);
        float4* o1 = reinterpret_cast<float4*>(out + obase + OW);
        o0[0] = make_float4(row0[0], row0[1], row0[2], row0[3]);
        o0[1] = make_float4(row0[4], row0[5], row0[6], row0[7]);
        o1[0] = make_float4(row1[0], row1[1], row1[2], row1[3]);
        o1[1] = make_float4(row1[4], row1[5], row1[6], row1[7]);
    }
}

extern "C" void kernel_launch(void* const* d_in, const int* in_sizes, int n_in,
                              void* d_out, int out_size, void* d_ws,
                              size_t ws_size, hipStream_t stream) {
    const float* LL = (const float*)d_in[0];
    const float* LH = (const float*)d_in[1];
    const float* HL = (const float*)d_in[2];
    const float* HH = (const float*)d_in[3];
    float* out = (float*)d_out;

    const int n_quads = in_sizes[0] / 4;  // 16*64*128*128/4 = 4,194,304

    const int threads = 256;
    const int blocks = 2048;  // grid-stride; ~8 quads per thread
    idwt_haar_kernel<<<blocks, threads, 0, stream>>>(LL, LH, HL, HH, out,
                                                     n_quads);
}